// Round 1
// baseline (169.843 us; speedup 1.0000x reference)
//
#include <hip/hip_runtime.h>
#include <math.h>

#define NB      64
#define NPTS    12288
#define KTOP    10
#define NKP     9
#define THREADS 256

struct Pair { float v; int i; };

__device__ __forceinline__ bool better(const Pair& a, const Pair& b) {
    // matches jax.lax.top_k ordering: value descending, index ascending on ties
    return (a.v > b.v) || (a.v == b.v && a.i < b.i);
}

__global__ __launch_bounds__(THREADS)
void pose_kernel(const float* __restrict__ pcld,   // [b, n, 3]
                 const float* __restrict__ kpts,   // [b, n, 8, 3]
                 const float* __restrict__ cpt,    // [b, n, 1, 3]
                 const float* __restrict__ seg,    // [b, n, 1]
                 const float* __restrict__ mesh,   // [b, 9, 3]
                 float* __restrict__ out)          // R[64,3,3] | t[64,3] | voted[64,9,3]
{
    const int b = blockIdx.x;
    const int t = threadIdx.x;

    __shared__ Pair  lists[THREADS][KTOP];   // 20480 B
    __shared__ float cands[NKP][KTOP][3];    // 1080 B
    __shared__ float voted[NKP][3];          // 108 B

    // ---- Phase A: per-thread top-10 over strided scan of seg[b] ----
    Pair loc[KTOP];
    #pragma unroll
    for (int j = 0; j < KTOP; ++j) { loc[j].v = -INFINITY; loc[j].i = 0x7fffffff; }
    const float* segb = seg + (size_t)b * NPTS;
    for (int i = t; i < NPTS; i += THREADS) {
        Pair c; c.v = segb[i]; c.i = i;
        if (better(c, loc[KTOP - 1])) {
            loc[KTOP - 1] = c;
            #pragma unroll
            for (int j = KTOP - 1; j > 0; --j) {
                if (better(loc[j], loc[j - 1])) { Pair tmp = loc[j]; loc[j] = loc[j - 1]; loc[j - 1] = tmp; }
                else break;
            }
        }
    }
    #pragma unroll
    for (int j = 0; j < KTOP; ++j) lists[t][j] = loc[j];
    __syncthreads();

    // ---- Phase B: LDS tree merge of sorted 10-lists ----
    for (int s = 1; s < THREADS; s <<= 1) {
        if ((t & (2 * s - 1)) == 0 && (t + s) < THREADS) {
            Pair m[KTOP];
            int a = 0, c2 = 0;
            #pragma unroll
            for (int j = 0; j < KTOP; ++j) {
                Pair pa = lists[t][a], pb = lists[t + s][c2];
                if (better(pa, pb)) { m[j] = pa; ++a; } else { m[j] = pb; ++c2; }
            }
            #pragma unroll
            for (int j = 0; j < KTOP; ++j) lists[t][j] = m[j];
        }
        __syncthreads();
    }
    // lists[0][0..9] now holds the top-10 (value-desc, idx-asc), identical
    // order to jax.lax.top_k -> gather order matches reference.

    // ---- Phase C: gather 9x10 candidate keypoints ----
    if (t < NKP * KTOP) {
        int j = t / KTOP;   // keypoint channel (0..7 = kpts offsets, 8 = cpt offset)
        int i = t % KTOP;   // candidate rank
        int p = lists[0][i].i;
        size_t base = (size_t)b * NPTS + p;
        float px = pcld[base * 3 + 0], py = pcld[base * 3 + 1], pz = pcld[base * 3 + 2];
        float ox, oy, oz;
        if (j < 8) {
            size_t kb = (base * 8 + j) * 3;
            ox = kpts[kb + 0]; oy = kpts[kb + 1]; oz = kpts[kb + 2];
        } else {
            size_t cb = base * 3;
            ox = cpt[cb + 0]; oy = cpt[cb + 1]; oz = cpt[cb + 2];
        }
        cands[j][i][0] = px + ox;
        cands[j][i][1] = py + oy;
        cands[j][i][2] = pz + oz;
    }
    __syncthreads();

    // ---- Phase D: sigma-clip clustering per keypoint (fp32, numpy order) ----
    if (t < NKP) {
        float mean[3] = {0.f, 0.f, 0.f};
        for (int i = 0; i < KTOP; ++i)
            for (int c = 0; c < 3; ++c) mean[c] += cands[t][i][c];
        for (int c = 0; c < 3; ++c) mean[c] *= (1.0f / KTOP);
        float var[3] = {0.f, 0.f, 0.f};
        for (int i = 0; i < KTOP; ++i)
            for (int c = 0; c < 3; ++c) { float d = cands[t][i][c] - mean[c]; var[c] += d * d; }
        float sd[3];
        for (int c = 0; c < 3; ++c) sd[c] = sqrtf(var[c] * (1.0f / KTOP));
        float wsum = 0.f, acc[3] = {0.f, 0.f, 0.f};
        for (int i = 0; i < KTOP; ++i) {
            bool in = true;
            for (int c = 0; c < 3; ++c) in = in && (fabsf(cands[t][i][c] - mean[c]) <= sd[c]);
            if (in) {
                wsum += 1.f;
                for (int c = 0; c < 3; ++c) acc[c] += cands[t][i][c];
            }
        }
        float inv = 1.f / (wsum + 1e-6f);
        for (int c = 0; c < 3; ++c) {
            float v = acc[c] * inv;
            voted[t][c] = v;
            out[NB * 9 + NB * 3 + ((size_t)b * NKP + t) * 3 + c] = v;  // kpts_voted at offset 768
        }
    }
    __syncthreads();

    // ---- Phase E: weighted Kabsch (w = 1), 3x3 SVD via Jacobi on H^T H, double ----
    if (t == 0) {
        const float* mb = mesh + (size_t)b * NKP * 3;
        double A[NKP][3], Bv[NKP][3];
        double cA[3] = {0, 0, 0}, cB[3] = {0, 0, 0};
        for (int n = 0; n < NKP; ++n) {
            for (int c = 0; c < 3; ++c) {
                A[n][c]  = (double)mb[n * 3 + c];
                Bv[n][c] = (double)voted[n][c];
                cA[c] += A[n][c];
                cB[c] += Bv[n][c];
            }
        }
        for (int c = 0; c < 3; ++c) { cA[c] /= NKP; cB[c] /= NKP; }

        double H[3][3] = {{0,0,0},{0,0,0},{0,0,0}};
        for (int n = 0; n < NKP; ++n)
            for (int i = 0; i < 3; ++i)
                for (int j = 0; j < 3; ++j)
                    H[i][j] += (A[n][i] - cA[i]) * (Bv[n][j] - cB[j]);

        // K = H^T H (symmetric PSD)
        double Km[3][3];
        for (int i = 0; i < 3; ++i)
            for (int j = 0; j < 3; ++j) {
                double s = 0;
                for (int l = 0; l < 3; ++l) s += H[l][i] * H[l][j];
                Km[i][j] = s;
            }

        double V[3][3] = {{1,0,0},{0,1,0},{0,0,1}};
        for (int sweep = 0; sweep < 20; ++sweep) {
            for (int p = 0; p < 2; ++p) {
                for (int q = p + 1; q < 3; ++q) {
                    double apq = Km[p][q];
                    double app = Km[p][p], aqq = Km[q][q];
                    if (fabs(apq) <= 1e-30 * (fabs(app) + fabs(aqq)) || apq == 0.0) continue;
                    double theta = (aqq - app) / (2.0 * apq);
                    double tj = ((theta >= 0.0) ? 1.0 : -1.0) / (fabs(theta) + sqrt(theta * theta + 1.0));
                    double cj = 1.0 / sqrt(tj * tj + 1.0);
                    double sj = tj * cj;
                    for (int l = 0; l < 3; ++l) {   // Km = Km * J
                        double klp = Km[l][p], klq = Km[l][q];
                        Km[l][p] = cj * klp - sj * klq;
                        Km[l][q] = sj * klp + cj * klq;
                    }
                    for (int l = 0; l < 3; ++l) {   // Km = J^T * Km
                        double kpl = Km[p][l], kql = Km[q][l];
                        Km[p][l] = cj * kpl - sj * kql;
                        Km[q][l] = sj * kpl + cj * kql;
                    }
                    for (int l = 0; l < 3; ++l) {   // V = V * J
                        double vlp = V[l][p], vlq = V[l][q];
                        V[l][p] = cj * vlp - sj * vlq;
                        V[l][q] = sj * vlp + cj * vlq;
                    }
                }
            }
        }

        double eig[3] = {Km[0][0], Km[1][1], Km[2][2]};
        int ord[3] = {0, 1, 2};
        // sort eigenvalues descending (3-element sort)
        if (eig[ord[0]] < eig[ord[1]]) { int tmp = ord[0]; ord[0] = ord[1]; ord[1] = tmp; }
        if (eig[ord[1]] < eig[ord[2]]) { int tmp = ord[1]; ord[1] = ord[2]; ord[2] = tmp; }
        if (eig[ord[0]] < eig[ord[1]]) { int tmp = ord[0]; ord[0] = ord[1]; ord[1] = tmp; }

        // det(H) -> reflection fix sign on smallest singular direction
        double detH =
            H[0][0] * (H[1][1] * H[2][2] - H[1][2] * H[2][1]) -
            H[0][1] * (H[1][0] * H[2][2] - H[1][2] * H[2][0]) +
            H[0][2] * (H[1][0] * H[2][1] - H[1][1] * H[2][0]);
        double dsign[3] = {1.0, 1.0, (detH < 0.0) ? -1.0 : 1.0};

        // U columns: u_i = H v_i / s_i ; R = sum_i d_i * v_i u_i^T
        double R[3][3] = {{0,0,0},{0,0,0},{0,0,0}};
        for (int k = 0; k < 3; ++k) {
            int c = ord[k];
            double s = sqrt(fmax(eig[c], 0.0));
            double invs = 1.0 / fmax(s, 1e-12);
            double u[3];
            for (int l = 0; l < 3; ++l) {
                double a = 0;
                for (int m = 0; m < 3; ++m) a += H[l][m] * V[m][c];
                u[l] = a * invs;
            }
            for (int r = 0; r < 3; ++r)
                for (int cc = 0; cc < 3; ++cc)
                    R[r][cc] += dsign[k] * V[r][c] * u[cc];
        }

        double tv[3];
        for (int c = 0; c < 3; ++c) {
            double a = 0;
            for (int m = 0; m < 3; ++m) a += R[c][m] * cA[m];
            tv[c] = cB[c] - a;
        }

        for (int r = 0; r < 3; ++r)
            for (int c = 0; c < 3; ++c)
                out[(size_t)b * 9 + r * 3 + c] = (float)R[r][c];         // batch_R
        for (int c = 0; c < 3; ++c)
            out[NB * 9 + (size_t)b * 3 + c] = (float)tv[c];              // batch_t at offset 576
    }
}

extern "C" void kernel_launch(void* const* d_in, const int* in_sizes, int n_in,
                              void* d_out, int out_size, void* d_ws, size_t ws_size,
                              hipStream_t stream) {
    const float* pcld = (const float*)d_in[0];   // [64,12288,3]
    const float* kpts = (const float*)d_in[1];   // [64,12288,8,3]
    const float* cpt  = (const float*)d_in[2];   // [64,12288,1,3]
    const float* seg  = (const float*)d_in[3];   // [64,12288,1]
    const float* mesh = (const float*)d_in[4];   // [64,9,3]
    float* out = (float*)d_out;                  // 576 (R) + 192 (t) + 1728 (voted)

    pose_kernel<<<NB, THREADS, 0, stream>>>(pcld, kpts, cpt, seg, mesh, out);
}

// Round 2
// 136.052 us; speedup vs baseline: 1.2484x; 1.2484x over previous
//
#include <hip/hip_runtime.h>
#include <math.h>

#define NB      64
#define NPTS    12288
#define KTOP    10
#define NKP     9
#define CHUNKS  8
#define CHUNK_N (NPTS / CHUNKS)   // 1536
#define T1      256
#define T2      128

struct Pair { float v; int i; };

__device__ __forceinline__ bool better(const Pair& a, const Pair& b) {
    // matches jax.lax.top_k ordering: value descending, index ascending on ties
    return (a.v > b.v) || (a.v == b.v && a.i < b.i);
}

__device__ __forceinline__ void push10(Pair (&loc)[KTOP], Pair c) {
    if (better(c, loc[KTOP - 1])) {
        loc[KTOP - 1] = c;
        #pragma unroll
        for (int j = KTOP - 1; j > 0; --j) {
            if (better(loc[j], loc[j - 1])) { Pair tmp = loc[j]; loc[j] = loc[j - 1]; loc[j - 1] = tmp; }
            else break;
        }
    }
}

__device__ __forceinline__ void merge10(const Pair* __restrict__ A,
                                        const Pair* __restrict__ B,
                                        Pair* __restrict__ D) {
    int a = 0, c = 0;
    #pragma unroll
    for (int j = 0; j < KTOP; ++j) {
        Pair pa = A[a], pb = B[c];
        if (better(pa, pb)) { D[j] = pa; ++a; } else { D[j] = pb; ++c; }
    }
}

// ---------------- Kernel 1: per-chunk partial top-10 ----------------
// grid = NB*CHUNKS blocks; block (b, chunk) scans 1536 consecutive seg values.
__global__ __launch_bounds__(T1)
void topk_part(const float* __restrict__ seg, Pair* __restrict__ part) {
    const int blk = blockIdx.x;
    const int b = blk >> 3;          // /CHUNKS
    const int chunk = blk & 7;       // %CHUNKS
    const int t = threadIdx.x;

    __shared__ Pair lists[T1][KTOP];  // 20480 B

    const float* segb = seg + (size_t)b * NPTS + (size_t)chunk * CHUNK_N;
    const int base = chunk * CHUNK_N;

    // 6 values per thread: one float4 (covers [0,1024)) + one float2 ([1024,1536))
    float4 a4 = ((const float4*)segb)[t];
    float2 a2 = ((const float2*)(segb + 1024))[t];

    Pair loc[KTOP];
    #pragma unroll
    for (int j = 0; j < KTOP; ++j) { loc[j].v = -INFINITY; loc[j].i = 0x7fffffff; }
    push10(loc, {a4.x, base + 4 * t + 0});
    push10(loc, {a4.y, base + 4 * t + 1});
    push10(loc, {a4.z, base + 4 * t + 2});
    push10(loc, {a4.w, base + 4 * t + 3});
    push10(loc, {a2.x, base + 1024 + 2 * t + 0});
    push10(loc, {a2.y, base + 1024 + 2 * t + 1});

    #pragma unroll
    for (int j = 0; j < KTOP; ++j) lists[t][j] = loc[j];
    __syncthreads();

    for (int s = 1; s < T1; s <<= 1) {
        if ((t & (2 * s - 1)) == 0 && (t + s) < T1) {
            Pair m[KTOP];
            merge10(lists[t], lists[t + s], m);
            #pragma unroll
            for (int j = 0; j < KTOP; ++j) lists[t][j] = m[j];
        }
        __syncthreads();
    }

    if (t < KTOP) part[(size_t)blk * KTOP + t] = lists[0][t];
}

// ---------------- Kernel 2: merge partials + gather + cluster + Kabsch ----------------
__global__ __launch_bounds__(T2)
void pose_finish(const float* __restrict__ pcld,   // [b, n, 3]
                 const float* __restrict__ kpts,   // [b, n, 8, 3]
                 const float* __restrict__ cpt,    // [b, n, 1, 3]
                 const float* __restrict__ mesh,   // [b, 9, 3]
                 const Pair*  __restrict__ part,   // [b, CHUNKS, 10]
                 float* __restrict__ out)          // R[64,3,3] | t[64,3] | voted[64,9,3]
{
    const int b = blockIdx.x;
    const int t = threadIdx.x;

    __shared__ Pair  l0[CHUNKS][KTOP];
    __shared__ Pair  m1[4][KTOP];
    __shared__ Pair  m2[2][KTOP];
    __shared__ Pair  top[KTOP];
    __shared__ float cands[NKP][KTOP][3];
    __shared__ float voted[NKP][3];

    if (t < CHUNKS * KTOP)
        l0[t / KTOP][t % KTOP] = part[(size_t)b * CHUNKS * KTOP + t];
    __syncthreads();

    if (t < 4) merge10(l0[2 * t], l0[2 * t + 1], m1[t]);
    __syncthreads();
    if (t < 2) merge10(m1[2 * t], m1[2 * t + 1], m2[t]);
    __syncthreads();
    if (t == 0) merge10(m2[0], m2[1], top);
    __syncthreads();
    // top[0..9] = batch-global top-10 (value-desc, idx-asc) == jax.lax.top_k order.

    // ---- gather 9x10 candidate keypoints ----
    if (t < NKP * KTOP) {
        int j = t / KTOP;   // keypoint channel (0..7 = kpts offsets, 8 = cpt offset)
        int i = t % KTOP;   // candidate rank
        int p = top[i].i;
        size_t base = (size_t)b * NPTS + p;
        float px = pcld[base * 3 + 0], py = pcld[base * 3 + 1], pz = pcld[base * 3 + 2];
        float ox, oy, oz;
        if (j < 8) {
            size_t kb = (base * 8 + j) * 3;
            ox = kpts[kb + 0]; oy = kpts[kb + 1]; oz = kpts[kb + 2];
        } else {
            size_t cb = base * 3;
            ox = cpt[cb + 0]; oy = cpt[cb + 1]; oz = cpt[cb + 2];
        }
        cands[j][i][0] = px + ox;
        cands[j][i][1] = py + oy;
        cands[j][i][2] = pz + oz;
    }
    __syncthreads();

    // ---- sigma-clip clustering per keypoint (fp32, numpy order) ----
    if (t < NKP) {
        float mean[3] = {0.f, 0.f, 0.f};
        for (int i = 0; i < KTOP; ++i)
            for (int c = 0; c < 3; ++c) mean[c] += cands[t][i][c];
        for (int c = 0; c < 3; ++c) mean[c] *= (1.0f / KTOP);
        float var[3] = {0.f, 0.f, 0.f};
        for (int i = 0; i < KTOP; ++i)
            for (int c = 0; c < 3; ++c) { float d = cands[t][i][c] - mean[c]; var[c] += d * d; }
        float sd[3];
        for (int c = 0; c < 3; ++c) sd[c] = sqrtf(var[c] * (1.0f / KTOP));
        float wsum = 0.f, acc[3] = {0.f, 0.f, 0.f};
        for (int i = 0; i < KTOP; ++i) {
            bool in = true;
            for (int c = 0; c < 3; ++c) in = in && (fabsf(cands[t][i][c] - mean[c]) <= sd[c]);
            if (in) {
                wsum += 1.f;
                for (int c = 0; c < 3; ++c) acc[c] += cands[t][i][c];
            }
        }
        float inv = 1.f / (wsum + 1e-6f);
        for (int c = 0; c < 3; ++c) {
            float v = acc[c] * inv;
            voted[t][c] = v;
            out[NB * 9 + NB * 3 + ((size_t)b * NKP + t) * 3 + c] = v;  // kpts_voted at offset 768
        }
    }
    __syncthreads();

    // ---- weighted Kabsch (w = 1), 3x3 SVD via Jacobi on H^T H, double ----
    if (t == 0) {
        const float* mb = mesh + (size_t)b * NKP * 3;
        double A[NKP][3], Bv[NKP][3];
        double cA[3] = {0, 0, 0}, cB[3] = {0, 0, 0};
        for (int n = 0; n < NKP; ++n) {
            for (int c = 0; c < 3; ++c) {
                A[n][c]  = (double)mb[n * 3 + c];
                Bv[n][c] = (double)voted[n][c];
                cA[c] += A[n][c];
                cB[c] += Bv[n][c];
            }
        }
        for (int c = 0; c < 3; ++c) { cA[c] /= NKP; cB[c] /= NKP; }

        double H[3][3] = {{0,0,0},{0,0,0},{0,0,0}};
        for (int n = 0; n < NKP; ++n)
            for (int i = 0; i < 3; ++i)
                for (int j = 0; j < 3; ++j)
                    H[i][j] += (A[n][i] - cA[i]) * (Bv[n][j] - cB[j]);

        // K = H^T H (symmetric PSD)
        double Km[3][3];
        for (int i = 0; i < 3; ++i)
            for (int j = 0; j < 3; ++j) {
                double s = 0;
                for (int l = 0; l < 3; ++l) s += H[l][i] * H[l][j];
                Km[i][j] = s;
            }

        double V[3][3] = {{1,0,0},{0,1,0},{0,0,1}};
        for (int sweep = 0; sweep < 8; ++sweep) {
            for (int p = 0; p < 2; ++p) {
                for (int q = p + 1; q < 3; ++q) {
                    double apq = Km[p][q];
                    double app = Km[p][p], aqq = Km[q][q];
                    if (fabs(apq) <= 1e-30 * (fabs(app) + fabs(aqq)) || apq == 0.0) continue;
                    double theta = (aqq - app) / (2.0 * apq);
                    double tj = ((theta >= 0.0) ? 1.0 : -1.0) / (fabs(theta) + sqrt(theta * theta + 1.0));
                    double cj = 1.0 / sqrt(tj * tj + 1.0);
                    double sj = tj * cj;
                    for (int l = 0; l < 3; ++l) {   // Km = Km * J
                        double klp = Km[l][p], klq = Km[l][q];
                        Km[l][p] = cj * klp - sj * klq;
                        Km[l][q] = sj * klp + cj * klq;
                    }
                    for (int l = 0; l < 3; ++l) {   // Km = J^T * Km
                        double kpl = Km[p][l], kql = Km[q][l];
                        Km[p][l] = cj * kpl - sj * kql;
                        Km[q][l] = sj * kpl + cj * kql;
                    }
                    for (int l = 0; l < 3; ++l) {   // V = V * J
                        double vlp = V[l][p], vlq = V[l][q];
                        V[l][p] = cj * vlp - sj * vlq;
                        V[l][q] = sj * vlp + cj * vlq;
                    }
                }
            }
        }

        double eig[3] = {Km[0][0], Km[1][1], Km[2][2]};
        int ord[3] = {0, 1, 2};
        if (eig[ord[0]] < eig[ord[1]]) { int tmp = ord[0]; ord[0] = ord[1]; ord[1] = tmp; }
        if (eig[ord[1]] < eig[ord[2]]) { int tmp = ord[1]; ord[1] = ord[2]; ord[2] = tmp; }
        if (eig[ord[0]] < eig[ord[1]]) { int tmp = ord[0]; ord[0] = ord[1]; ord[1] = tmp; }

        double detH =
            H[0][0] * (H[1][1] * H[2][2] - H[1][2] * H[2][1]) -
            H[0][1] * (H[1][0] * H[2][2] - H[1][2] * H[2][0]) +
            H[0][2] * (H[1][0] * H[2][1] - H[1][1] * H[2][0]);
        double dsign[3] = {1.0, 1.0, (detH < 0.0) ? -1.0 : 1.0};

        double R[3][3] = {{0,0,0},{0,0,0},{0,0,0}};
        for (int k = 0; k < 3; ++k) {
            int c = ord[k];
            double s = sqrt(fmax(eig[c], 0.0));
            double invs = 1.0 / fmax(s, 1e-12);
            double u[3];
            for (int l = 0; l < 3; ++l) {
                double a = 0;
                for (int m = 0; m < 3; ++m) a += H[l][m] * V[m][c];
                u[l] = a * invs;
            }
            for (int r = 0; r < 3; ++r)
                for (int cc = 0; cc < 3; ++cc)
                    R[r][cc] += dsign[k] * V[r][c] * u[cc];
        }

        double tv[3];
        for (int c = 0; c < 3; ++c) {
            double a = 0;
            for (int m = 0; m < 3; ++m) a += R[c][m] * cA[m];
            tv[c] = cB[c] - a;
        }

        for (int r = 0; r < 3; ++r)
            for (int c = 0; c < 3; ++c)
                out[(size_t)b * 9 + r * 3 + c] = (float)R[r][c];         // batch_R
        for (int c = 0; c < 3; ++c)
            out[NB * 9 + (size_t)b * 3 + c] = (float)tv[c];              // batch_t at offset 576
    }
}

extern "C" void kernel_launch(void* const* d_in, const int* in_sizes, int n_in,
                              void* d_out, int out_size, void* d_ws, size_t ws_size,
                              hipStream_t stream) {
    const float* pcld = (const float*)d_in[0];   // [64,12288,3]
    const float* kpts = (const float*)d_in[1];   // [64,12288,8,3]
    const float* cpt  = (const float*)d_in[2];   // [64,12288,1,3]
    const float* seg  = (const float*)d_in[3];   // [64,12288,1]
    const float* mesh = (const float*)d_in[4];   // [64,9,3]
    float* out = (float*)d_out;                  // 576 (R) + 192 (t) + 1728 (voted)
    Pair* part = (Pair*)d_ws;                    // [64][8][10] Pairs = 40960 B

    topk_part<<<NB * CHUNKS, T1, 0, stream>>>(seg, part);
    pose_finish<<<NB, T2, 0, stream>>>(pcld, kpts, cpt, mesh, part, out);
}